// Round 2
// baseline (340.953 us; speedup 1.0000x reference)
//
#include <hip/hip_runtime.h>
#include <math.h>

// Fully-fused pipeline, one heavyweight kernel + prep + softmax.
// R2 change: SINGLE-WAVE WORKGROUPS. R1 showed occupancy pinned at ~1
// block/CU regardless of grid/VGPR/LDS -> limiter is block-granular.
// Each 16-series tile needs no inter-wave communication (wave-private LDS
// tile, barrier-free), so blocks are now 64 threads = 1 wave. 2048
// independent blocks, zero __syncthreads, one partials row per wave.
//   k0    : w2 [64][32][3] -> w2b bf16 [64][96] (k=d*32+ci); w3 -> w3b bf16
//   k_fused (1 wave / 16 series): conv1+pool1 per-lane in EXACT MFMA-A
//     layout (lane(quad,lm) -> series lm, channels quad*8..+7) -> conv2 =
//     16x16x32 MFMA vs w2b -> bias+relu+pool2+relu per-lane
//     (D: row=series quad*4+r, col=c2 lm) -> packed bf16 via wave-private
//     LDS tile (the only transpose) -> conv3 GEMM (K=256) vs w3b -> relu
//     -> logits partials vs wl -> wave butterfly -> partials[2048][3]
//   k_soft: 1 block: logits = sum of 8 partials + bl, softmax -> out [256][3]
// No h1/h2/feat intermediates in HBM: only x (159 MB) is read.

typedef __attribute__((ext_vector_type(8))) short bf16x8;
typedef __attribute__((ext_vector_type(4))) float f32x4;

__device__ __forceinline__ ushort f2bf(float f) {
    union { float f; uint u; } c; c.f = f;
    return (ushort)((c.u + 0x7FFFu + ((c.u >> 16) & 1u)) >> 16);   // RNE
}

#define S2 264   // sh2 row stride (ushorts): 528B rows, 16B-aligned

__global__ void k0_prep(const float* __restrict__ w2, ushort* __restrict__ w2b,
                        const float* __restrict__ w3, ushort* __restrict__ w3b) {
    int i = blockIdx.x * 256 + threadIdx.x;
    if (i < 6144) {                     // w2[c][ci][d] -> w2b[c][d*32+ci]
        int c = i / 96, r = i - c * 96;
        int ci = r / 3, d = r - ci * 3;
        w2b[c * 96 + d * 32 + ci] = f2bf(w2[i]);
    }
    int j = i - 6144;
    if (j >= 0 && j < 32768) w3b[j] = f2bf(w3[j]);
}

__global__ __launch_bounds__(64) void k_fused(
    const float* __restrict__ x,     // [32768][1216]
    const float* __restrict__ w1,    // [32][10]
    const float* __restrict__ b1,    // [32]
    const ushort* __restrict__ w2b,  // [64][96]
    const float* __restrict__ b2,    // [64]
    const ushort* __restrict__ w3b,  // [128][256]
    const float* __restrict__ b3,    // [128]
    const float* __restrict__ wl,    // [3][16384]
    float* __restrict__ partials)    // [2048][3]
{
    __shared__ ushort sh2[16 * S2];         // wave-private 16x256 bf16 tile
    const int lane = threadIdx.x;           // 64-thread block = exactly 1 wave
    const int lm   = lane & 15, quad = lane >> 4;
    const int bn0  = blockIdx.x * 16;
    const float* xr = x + (size_t)(bn0 + lm) * 1216;

    // hoist this lane's conv1 weights: channels quad*8..quad*8+7
    float wv[8][10], b1v[8];
    #pragma unroll
    for (int h = 0; h < 8; ++h) {
        const float* wr = w1 + (quad * 8 + h) * 10;     // 4 distinct addrs/wave
        #pragma unroll
        for (int kk = 0; kk < 5; ++kk) {
            float2 t = *(const float2*)(wr + 2 * kk);
            wv[h][2*kk] = t.x; wv[h][2*kk+1] = t.y;
        }
        b1v[h] = b1[quad * 8 + h];
    }
    float bias2[4];
    #pragma unroll
    for (int nt = 0; nt < 4; ++nt) bias2[nt] = b2[nt * 16 + lm];

    // ---- conv1 -> conv2 MFMA -> pool2, q = conv2 output position
    f32x4 cur[4];
    #pragma unroll
    for (int nt = 0; nt < 4; ++nt) cur[nt] = (f32x4){-3e38f,-3e38f,-3e38f,-3e38f};
    uint2 pk[4][4];                         // packed pooled bf16 [nt][r]

    for (int q = 0; q < 10; ++q) {          // dynamic: keep icache small
        f32x4 acc[4];
        #pragma unroll
        for (int nt = 0; nt < 4; ++nt) acc[nt] = (f32x4){0.f,0.f,0.f,0.f};

        #pragma unroll
        for (int kc = 0; kc < 3; ++kc) {
            const int p = 3 * q + kc;       // conv1-pooled position 0..29
            const int base = 40 * p - 4;    // 16B-aligned window
            const float4* xp4 = (const float4*)(xr + base);
            // rolling 16-float window [8dt .. 8dt+15]; taps are floats 3..12
            float4 c0 = (base >= 0) ? xp4[0]            // uniform branch
                                    : make_float4(0.f, 0.f, 0.f, 0.f); // p==0 pad
            float4 c1 = xp4[1], c2 = xp4[2], c3 = xp4[3];
            float mx[8];
            #pragma unroll
            for (int h = 0; h < 8; ++h) mx[h] = 0.f;    // relu folded into pool
            #pragma unroll
            for (int dt = 0; dt < 5; ++dt) {            // conv1 K=10 s=8 p=1 + pool5
                const float xv[10] = {c0.w, c1.x, c1.y, c1.z, c1.w,
                                      c2.x, c2.y, c2.z, c2.w, c3.x};
                float a[8];
                #pragma unroll
                for (int h = 0; h < 8; ++h) a[h] = b1v[h];
                #pragma unroll
                for (int k = 0; k < 10; ++k)
                    #pragma unroll
                    for (int h = 0; h < 8; ++h)
                        a[h] = fmaf(wv[h][k], xv[k], a[h]);
                #pragma unroll
                for (int h = 0; h < 8; ++h) mx[h] = fmaxf(mx[h], a[h]);
                if (dt < 4) {                           // roll by 8 floats
                    c0 = c2; c1 = c3;
                    c2 = xp4[2*dt + 4]; c3 = xp4[2*dt + 5];
                }
            }
            union { ushort u[8]; bf16x8 v; } af;
            #pragma unroll
            for (int h = 0; h < 8; ++h) af.u[h] = f2bf(mx[h]);
            #pragma unroll
            for (int nt = 0; nt < 4; ++nt) {   // w2b frags from L1 (12KB hot)
                bf16x8 bfr = *(const bf16x8*)(w2b + (nt*16+lm)*96 + kc*32 + quad*8);
                acc[nt] = __builtin_amdgcn_mfma_f32_16x16x32_bf16(af.v, bfr, acc[nt], 0, 0, 0);
            }
        }

        // pool2 windows over q: {0,1},{2,3,4},{5,6,7},{8,9}  (wave-uniform)
        const bool fresh = (q == 0 || q == 2 || q == 5 || q == 8);
        #pragma unroll
        for (int nt = 0; nt < 4; ++nt)
            #pragma unroll
            for (int r = 0; r < 4; ++r)
                cur[nt][r] = fresh ? acc[nt][r] : fmaxf(cur[nt][r], acc[nt][r]);

        if (q == 1 || q == 4 || q == 7 || q == 9) {     // window end
            const int w = (q == 1) ? 0 : (q == 4) ? 1 : (q == 7) ? 2 : 3;
            #pragma unroll
            for (int nt = 0; nt < 4; ++nt)
                #pragma unroll
                for (int r = 0; r < 4; ++r) {
                    float f = fmaxf(cur[nt][r] + bias2[nt], 0.f);
                    uint hb = (uint)f2bf(f);
                    if (w == 0)      pk[nt][r].x  = hb;
                    else if (w == 1) pk[nt][r].x |= hb << 16;
                    else if (w == 2) pk[nt][r].y  = hb;
                    else             pk[nt][r].y |= hb << 16;
                }
        }
    }

    // ---- transpose via wave-private LDS: rows = series, k = c2*4 + lp
    // (no barrier: same wave writes and reads; compiler inserts lgkmcnt)
    #pragma unroll
    for (int nt = 0; nt < 4; ++nt)
        #pragma unroll
        for (int r = 0; r < 4; ++r)
            *(uint2*)(sh2 + (quad*4 + r) * S2 + (nt*16 + lm) * 4) = pk[nt][r];

    // ---- conv3 GEMM (16 series x 128 cols, K=256) + logits partials
    bf16x8 afr[8];
    #pragma unroll
    for (int kc = 0; kc < 8; ++kc)          // A-frag: row lm, 16B contiguous
        afr[kc] = *(const bf16x8*)(sh2 + lm * S2 + kc * 32 + quad * 8);

    const int node0 = bn0 & 127;
    const float* wlr = wl + (node0 + quad * 4) * 128 + lm;
    float a0 = 0.f, a1 = 0.f, a2 = 0.f;
    for (int nt3 = 0; nt3 < 8; ++nt3) {     // dynamic: small icache
        f32x4 acc3 = (f32x4){0.f, 0.f, 0.f, 0.f};
        const ushort* bb = w3b + (size_t)(nt3 * 16 + lm) * 256 + quad * 8;
        #pragma unroll
        for (int kc = 0; kc < 8; ++kc) {
            bf16x8 bf3 = *(const bf16x8*)(bb + kc * 32);
            acc3 = __builtin_amdgcn_mfma_f32_16x16x32_bf16(afr[kc], bf3, acc3, 0, 0, 0);
        }
        const float b3v = b3[nt3 * 16 + lm];
        #pragma unroll
        for (int r = 0; r < 4; ++r) {       // feat value, never materialized
            float f = fmaxf(acc3[r] + b3v, 0.f);
            const float* wp = wlr + r * 128 + nt3 * 16;
            a0 = fmaf(f, wp[0],     a0);
            a1 = fmaf(f, wp[16384], a1);
            a2 = fmaf(f, wp[32768], a2);
        }
    }

    #pragma unroll
    for (int off = 32; off > 0; off >>= 1) {
        a0 += __shfl_xor(a0, off);
        a1 += __shfl_xor(a1, off);
        a2 += __shfl_xor(a2, off);
    }
    if (lane == 0) {
        float* pr = partials + blockIdx.x * 3;
        pr[0] = a0; pr[1] = a1; pr[2] = a2;
    }
}

// logits = sum of 8 partials rows + bl -> softmax
__global__ void k_soft(const float* __restrict__ partials,
                       const float* __restrict__ bl,
                       float* __restrict__ out) {
    const int b = threadIdx.x;      // 256 batches, 1 block
    float l0 = bl[0], l1 = bl[1], l2 = bl[2];
    #pragma unroll
    for (int j = 0; j < 8; ++j) {
        const float* pr = partials + (8*b + j) * 3;
        l0 += pr[0]; l1 += pr[1]; l2 += pr[2];
    }
    float m  = fmaxf(l0, fmaxf(l1, l2));
    float e0 = expf(l0 - m), e1 = expf(l1 - m), e2 = expf(l2 - m);
    float s  = e0 + e1 + e2;
    out[b*3+0] = e0 / s; out[b*3+1] = e1 / s; out[b*3+2] = e2 / s;
}

extern "C" void kernel_launch(void* const* d_in, const int* in_sizes, int n_in,
                              void* d_out, int out_size, void* d_ws, size_t ws_size,
                              hipStream_t stream) {
    const float* x  = (const float*)d_in[0];
    const float* w1 = (const float*)d_in[1];
    const float* b1 = (const float*)d_in[2];
    const float* w2 = (const float*)d_in[3];
    const float* b2 = (const float*)d_in[4];
    const float* w3 = (const float*)d_in[5];
    const float* b3 = (const float*)d_in[6];
    const float* wl = (const float*)d_in[7];
    const float* bl = (const float*)d_in[8];
    float* out = (float*)d_out;

    // tiny ws: w2b 12KB | w3b 64KB | partials 24KB
    ushort* w2b      = (ushort*)d_ws;
    ushort* w3b      = (ushort*)((char*)d_ws + 16384);
    float*  partials = (float*)((char*)d_ws + 16384 + 65536);

    k0_prep<<<152, 256, 0, stream>>>(w2, w2b, w3, w3b);
    k_fused<<<2048, 64, 0, stream>>>(x, w1, b1, w2b, b2, w3b, b3, wl, partials);
    k_soft<<<1, 256, 0, stream>>>(partials, bl, out);
}

// Round 3
// 295.629 us; speedup vs baseline: 1.1533x; 1.1533x over previous
//
#include <hip/hip_runtime.h>
#include <math.h>

// Fully-fused pipeline, one heavyweight kernel + prep + softmax.
// R3: revert to the proven R0 structure (512 blocks x 256 thr, 4 independent
// waves/block, 16 series per wave) and SOFTWARE-PIPELINE the x window loads:
// two register window buffers (A/B) with window p+1's 12 loads issued while
// window p's ~480-FMA conv1 block computes (q-loop unrolled x2 so buffer
// roles are static). Windows slimmed to 42 floats (1 + 10xfloat4 + 1): the
// only pad element is float -1, handled once in the prologue -> no in-loop
// pad branch, no negative-address loads. Pool2 results go straight to the
// wave-private LDS tile at window close (ds_write_b16), freeing the pk[]
// packing registers to pay for the second buffer.
// Inner arithmetic order is bitwise identical to R0 (absmax unchanged).
//   k0    : w2 [64][32][3] -> w2b bf16 [64][96] (k=d*32+ci); w3 -> w3b bf16
//   k_fused: conv1+pool1 per-lane in EXACT MFMA-A layout -> conv2 = 16x16x32
//     MFMA vs w2b -> bias+relu+pool2 -> bf16 into wave-private LDS tile (the
//     only transpose) -> conv3 GEMM (K=256) vs w3b -> relu -> logits partials
//     vs wl -> wave butterfly -> per-block partial[512][3]
//   k_soft: 1 block: logits = sum of 2 partials + bl, softmax -> out [256][3]

typedef __attribute__((ext_vector_type(8))) short bf16x8;
typedef __attribute__((ext_vector_type(4))) float f32x4;

__device__ __forceinline__ ushort f2bf(float f) {
    union { float f; uint u; } c; c.f = f;
    return (ushort)((c.u + 0x7FFFu + ((c.u >> 16) & 1u)) >> 16);   // RNE
}

#define S2 264   // sh2 row stride (ushorts): 528B rows, 16B-aligned

__global__ void k0_prep(const float* __restrict__ w2, ushort* __restrict__ w2b,
                        const float* __restrict__ w3, ushort* __restrict__ w3b) {
    int i = blockIdx.x * 256 + threadIdx.x;
    if (i < 6144) {                     // w2[c][ci][d] -> w2b[c][d*32+ci]
        int c = i / 96, r = i - c * 96;
        int ci = r / 3, d = r - ci * 3;
        w2b[c * 96 + d * 32 + ci] = f2bf(w2[i]);
    }
    int j = i - 6144;
    if (j >= 0 && j < 32768) w3b[j] = f2bf(w3[j]);
}

// ---- window tap access: tap T in [-1,40] of window p = x[40p + T] ----
#define XTC(T) ((T) < 0 ? 0 : (T) > 39 ? 39 : (T))      // dead-branch-safe idx
#define XT(N, T) ((T) < 0 ? N##_lo : (T) >= 40 ? N##_hi :                      \
    ((XTC(T)) & 3) == 0 ? N##_c[(XTC(T)) >> 2].x :                             \
    ((XTC(T)) & 3) == 1 ? N##_c[(XTC(T)) >> 2].y :                             \
    ((XTC(T)) & 3) == 2 ? N##_c[(XTC(T)) >> 2].z : N##_c[(XTC(T)) >> 2].w)

// issue window p's 12 loads (1 dword + 10 dwordx4 + 1 dword), p >= 1
#define LOADW(N, p_) do {                                                      \
    const int p__ = (p_);                                                      \
    N##_lo = xr[40 * p__ - 1];                                                 \
    _Pragma("unroll") for (int i_ = 0; i_ < 10; ++i_)                          \
        N##_c[i_] = xp4[10 * p__ + i_];                                        \
    N##_hi = xr[40 * p__ + 40];                                                \
} while (0)

// conv1 (K=10,s=8,p=1) + relu + pool5 for 8 channels, pack bf16, MFMA vs w2b
#define WINCOMP(N, kc_) do {                                                   \
    float mx_[8];                                                              \
    _Pragma("unroll") for (int h = 0; h < 8; ++h) mx_[h] = 0.f;                \
    _Pragma("unroll") for (int dt = 0; dt < 5; ++dt) {                         \
        float a_[8];                                                           \
        _Pragma("unroll") for (int h = 0; h < 8; ++h) a_[h] = b1v[h];          \
        _Pragma("unroll") for (int k = 0; k < 10; ++k) {                       \
            const float xv_ = XT(N, 8 * dt + k - 1);                           \
            _Pragma("unroll") for (int h = 0; h < 8; ++h)                      \
                a_[h] = fmaf(wv[h][k], xv_, a_[h]);                            \
        }                                                                      \
        _Pragma("unroll") for (int h = 0; h < 8; ++h)                          \
            mx_[h] = fmaxf(mx_[h], a_[h]);                                     \
    }                                                                          \
    union { ushort u[8]; bf16x8 v; } af_;                                      \
    _Pragma("unroll") for (int h = 0; h < 8; ++h) af_.u[h] = f2bf(mx_[h]);     \
    _Pragma("unroll") for (int nt = 0; nt < 4; ++nt) {                         \
        bf16x8 bfr_ = *(const bf16x8*)(w2b + (nt*16 + lm)*96 + (kc_)*32 + quad*8); \
        acc[nt] = __builtin_amdgcn_mfma_f32_16x16x32_bf16(af_.v, bfr_, acc[nt], 0, 0, 0); \
    }                                                                          \
} while (0)

// pool2 over q: windows {0,1},{2,3,4},{5,6,7},{8,9}; write tile slot at close
#define POOLQ(q_) do {                                                         \
    const int q__ = (q_);                                                      \
    const bool fresh_ = (q__ == 0) || (q__ == 2) || (q__ == 5) || (q__ == 8);  \
    _Pragma("unroll") for (int nt = 0; nt < 4; ++nt)                           \
        _Pragma("unroll") for (int r = 0; r < 4; ++r)                          \
            cur[nt][r] = fresh_ ? acc[nt][r] : fmaxf(cur[nt][r], acc[nt][r]);  \
    if ((q__ == 1) || (q__ == 4) || (q__ == 7) || (q__ == 9)) {                \
        const int w_ = (q__ == 1) ? 0 : (q__ == 4) ? 1 : (q__ == 7) ? 2 : 3;   \
        _Pragma("unroll") for (int nt = 0; nt < 4; ++nt)                       \
            _Pragma("unroll") for (int r = 0; r < 4; ++r) {                    \
                float f_ = fmaxf(cur[nt][r] + bias2[nt], 0.f);                 \
                shw[(quad*4 + r)*S2 + (nt*16 + lm)*4 + w_] = f2bf(f_);         \
            }                                                                  \
    }                                                                          \
} while (0)

__global__ __launch_bounds__(256, 2) void k_fused(
    const float* __restrict__ x,     // [32768][1216]
    const float* __restrict__ w1,    // [32][10]
    const float* __restrict__ b1,    // [32]
    const ushort* __restrict__ w2b,  // [64][96]
    const float* __restrict__ b2,    // [64]
    const ushort* __restrict__ w3b,  // [128][256]
    const float* __restrict__ b3,    // [128]
    const float* __restrict__ wl,    // [3][16384]
    float* __restrict__ partials)    // [512][3]
{
    __shared__ ushort sh2[4 * 16 * S2];     // wave-private 16x256 bf16 tiles
    __shared__ float red[4][3];
    const int wave = threadIdx.x >> 6, lane = threadIdx.x & 63;
    const int lm   = lane & 15, quad = lane >> 4;
    const int bn0  = blockIdx.x * 64 + wave * 16;
    const float* xr = x + (size_t)(bn0 + lm) * 1216;
    const float4* xp4 = (const float4*)xr;
    ushort* shw = sh2 + wave * 16 * S2;

    // hoist this lane's conv1 weights: channels quad*8..quad*8+7
    float wv[8][10], b1v[8];
    #pragma unroll
    for (int h = 0; h < 8; ++h) {
        const float* wr = w1 + (quad * 8 + h) * 10;     // 4 distinct addrs/wave
        #pragma unroll
        for (int kk = 0; kk < 5; ++kk) {
            float2 t = *(const float2*)(wr + 2 * kk);
            wv[h][2*kk] = t.x; wv[h][2*kk+1] = t.y;
        }
        b1v[h] = b1[quad * 8 + h];
    }
    float bias2[4];
    #pragma unroll
    for (int nt = 0; nt < 4; ++nt) bias2[nt] = b2[nt * 16 + lm];

    // ---- pipelined conv1 -> conv2 MFMA -> pool2 ----
    float A_lo, A_hi, B_lo, B_hi;
    float4 A_c[10], B_c[10];
    f32x4 cur[4], acc[4];
    #pragma unroll
    for (int nt = 0; nt < 4; ++nt) cur[nt] = (f32x4){-3e38f,-3e38f,-3e38f,-3e38f};

    // prologue: window 0 (only pad element is float -1 -> lo = 0)
    A_lo = 0.f;
    #pragma unroll
    for (int i = 0; i < 10; ++i) A_c[i] = xp4[i];
    A_hi = xr[40];

    for (int t = 0; t < 5; ++t) {           // q = 2t, 2t+1 (buffer roles swap)
        const int q0 = 2 * t;
        #pragma unroll
        for (int nt = 0; nt < 4; ++nt) acc[nt] = (f32x4){0.f,0.f,0.f,0.f};
        LOADW(B, 3*q0 + 1);  WINCOMP(A, 0);
        LOADW(A, 3*q0 + 2);  WINCOMP(B, 1);
        LOADW(B, 3*q0 + 3);  WINCOMP(A, 2);
        POOLQ(q0);
        #pragma unroll
        for (int nt = 0; nt < 4; ++nt) acc[nt] = (f32x4){0.f,0.f,0.f,0.f};
        LOADW(A, 3*q0 + 4);  WINCOMP(B, 0);
        LOADW(B, 3*q0 + 5);  WINCOMP(A, 1);
        if (t < 4) LOADW(A, 3*q0 + 6);      // no window 30
        WINCOMP(B, 2);
        POOLQ(q0 + 1);
    }

    // ---- conv3 GEMM (16 series x 128 cols, K=256) + logits partials
    // (tile written by this wave only; compiler orders ds_write->ds_read)
    bf16x8 afr[8];
    #pragma unroll
    for (int kc = 0; kc < 8; ++kc)          // A-frag: row lm, 16B contiguous
        afr[kc] = *(const bf16x8*)(shw + lm * S2 + kc * 32 + quad * 8);

    const int node0 = bn0 & 127;
    const float* wlr = wl + (node0 + quad * 4) * 128 + lm;
    float a0 = 0.f, a1 = 0.f, a2 = 0.f;
    for (int nt3 = 0; nt3 < 8; ++nt3) {     // dynamic: small icache
        f32x4 acc3 = (f32x4){0.f, 0.f, 0.f, 0.f};
        const ushort* bb = w3b + (size_t)(nt3 * 16 + lm) * 256 + quad * 8;
        #pragma unroll
        for (int kc = 0; kc < 8; ++kc) {
            bf16x8 bf3 = *(const bf16x8*)(bb + kc * 32);
            acc3 = __builtin_amdgcn_mfma_f32_16x16x32_bf16(afr[kc], bf3, acc3, 0, 0, 0);
        }
        const float b3v = b3[nt3 * 16 + lm];
        #pragma unroll
        for (int r = 0; r < 4; ++r) {       // feat value, never materialized
            float f = fmaxf(acc3[r] + b3v, 0.f);
            const float* wp = wlr + r * 128 + nt3 * 16;
            a0 = fmaf(f, wp[0],     a0);
            a1 = fmaf(f, wp[16384], a1);
            a2 = fmaf(f, wp[32768], a2);
        }
    }

    #pragma unroll
    for (int off = 32; off > 0; off >>= 1) {
        a0 += __shfl_xor(a0, off);
        a1 += __shfl_xor(a1, off);
        a2 += __shfl_xor(a2, off);
    }
    if (lane == 0) { red[wave][0] = a0; red[wave][1] = a1; red[wave][2] = a2; }
    __syncthreads();
    if (threadIdx.x < 3) {
        float s = red[0][threadIdx.x] + red[1][threadIdx.x]
                + red[2][threadIdx.x] + red[3][threadIdx.x];
        partials[blockIdx.x * 3 + threadIdx.x] = s;
    }
}

// logits = partials[2b] + partials[2b+1] + bl -> softmax
__global__ void k_soft(const float* __restrict__ partials,
                       const float* __restrict__ bl,
                       float* __restrict__ out) {
    const int b = threadIdx.x;      // 256 batches, 1 block
    float l0 = partials[(2*b)*3+0] + partials[(2*b+1)*3+0] + bl[0];
    float l1 = partials[(2*b)*3+1] + partials[(2*b+1)*3+1] + bl[1];
    float l2 = partials[(2*b)*3+2] + partials[(2*b+1)*3+2] + bl[2];
    float m  = fmaxf(l0, fmaxf(l1, l2));
    float e0 = expf(l0 - m), e1 = expf(l1 - m), e2 = expf(l2 - m);
    float s  = e0 + e1 + e2;
    out[b*3+0] = e0 / s; out[b*3+1] = e1 / s; out[b*3+2] = e2 / s;
}

extern "C" void kernel_launch(void* const* d_in, const int* in_sizes, int n_in,
                              void* d_out, int out_size, void* d_ws, size_t ws_size,
                              hipStream_t stream) {
    const float* x  = (const float*)d_in[0];
    const float* w1 = (const float*)d_in[1];
    const float* b1 = (const float*)d_in[2];
    const float* w2 = (const float*)d_in[3];
    const float* b2 = (const float*)d_in[4];
    const float* w3 = (const float*)d_in[5];
    const float* b3 = (const float*)d_in[6];
    const float* wl = (const float*)d_in[7];
    const float* bl = (const float*)d_in[8];
    float* out = (float*)d_out;

    // tiny ws: w2b 12KB | w3b 64KB | partials 6KB
    ushort* w2b      = (ushort*)d_ws;
    ushort* w3b      = (ushort*)((char*)d_ws + 16384);
    float*  partials = (float*)((char*)d_ws + 16384 + 65536);

    k0_prep<<<152, 256, 0, stream>>>(w2, w2b, w3, w3b);
    k_fused<<<512, 256, 0, stream>>>(x, w1, b1, w2b, b2, w3b, b3, wl, partials);
    k_soft<<<1, 256, 0, stream>>>(partials, bl, out);
}